// Round 3
// baseline (149.499 us; speedup 1.0000x reference)
//
#include <hip/hip_runtime.h>

// ROIPatchExtractor: B=32, C=3, H=W=448, 2x2 patches -> N=128 samples.
// Composed separable bilinear (patch->448 upsample, then ROI crop+resize):
// each output row/col = weighted 3-tap sum of consecutive patch rows/cols.
// Two-pass per block: horizontal pass interpolates each needed patch row once
// into LDS (float4 lanes), vertical pass = 3x ds_read_b128 + dwordx4 store.
// Thread layout: 448 threads = 112 column-quads (q=tid%112, cols 4q..4q+3)
//                x 4 row-subsets (sub=tid/112, rows sub+4j of the 16-row tile).

#define IMG 448
#define PATCH 224
#define ROWS 16
#define MAXPR 12   // patch rows per 16-output-row tile: <= 8+3
#define RPAD 452   // hrow stride in floats (16B-aligned)

__device__ inline float4 make_entry(int t, int crop, int off) {
    // stage 2: output coord t -> up-image coords u0,u1 with weight wy
    float cf = (float)crop;
    float s = ((float)t + 0.5f) * cf / 448.0f - 0.5f;
    s = fminf(fmaxf(s, 0.0f), cf - 1.0f);
    int i0 = (int)s;                 // s >= 0, trunc == floor
    int i1 = min(i0 + 1, crop - 1);
    float wy = s - (float)i0;
    int u0 = off + i0;
    int u1 = off + i1;
    // stage 1: up coord u -> patch coord: s1 = 0.5*u - 0.25, clamp [0,223]
    float t0 = fminf(fmaxf(0.5f * (float)u0 - 0.25f, 0.0f), 223.0f);
    int a0 = (int)t0;
    int a1 = min(a0 + 1, 223);
    float f0 = t0 - (float)a0;
    float t1 = fminf(fmaxf(0.5f * (float)u1 - 0.25f, 0.0f), 223.0f);
    int b0 = (int)t1;
    int b1 = min(b0 + 1, 223);
    float f1 = t1 - (float)b0;
    // fold 4 taps into 3 slots relative to a0 (footprint <= a0+2)
    float g0 = (1.0f - wy) * (1.0f - f0);
    float g1 = (1.0f - wy) * f0;
    float g2 = wy * (1.0f - f1);
    float g3 = wy * f1;
    float w0 = g0, w1 = 0.0f, w2 = 0.0f;
    if (a1 == a0) w0 += g1; else w1 += g1;
    if (b0 == a0) w0 += g2; else w1 += g2;
    int ob1 = b1 - a0;
    if (ob1 == 0) w0 += g3; else if (ob1 == 1) w1 += g3; else w2 += g3;
    float4 e;
    e.x = w0; e.y = w1; e.z = w2;
    e.w = __int_as_float(a0);        // patch-local base index [0,223]
    return e;
}

__global__ __launch_bounds__(448)
void roi_patch_kernel(const float* __restrict__ x,
                      const int* __restrict__ tops,
                      const int* __restrict__ lefts,
                      const int* __restrict__ crop_hs,
                      const int* __restrict__ crop_ws,
                      float* __restrict__ out,
                      int out_size) {
    __shared__ __align__(16) float hrow[MAXPR][RPAD];

    const int n   = blockIdx.y;
    const int y0  = blockIdx.x * ROWS;
    const int tid = threadIdx.x;
    const int b   = n >> 2;
    const int gi  = (n >> 1) & 1;
    const int gj  = n & 1;

    const int ch = crop_hs[n], cw = crop_ws[n];
    const int tp = tops[n],    lf = lefts[n];

    const int q   = tid % 112;   // column quad: cols 4q..4q+3
    const int sub = tid / 112;   // row subset: rows sub + 4j

    // patch_indices tail (float values; harness reads flat buffer as f32)
    if (blockIdx.x == 0 && n == 0 && tid < 128) {
        out[(size_t)out_size - 128 + tid] = (float)(tid & 3);
    }

    // column entries (registers, statically indexed)
    float cwx[4], cwy[4], cwz[4];
    int ci0[4], ci1[4], ci2[4];
    #pragma unroll
    for (int j = 0; j < 4; ++j) {
        float4 e = make_entry(4 * q + j, cw, lf);
        cwx[j] = e.x; cwy[j] = e.y; cwz[j] = e.z;
        int ca = __float_as_int(e.w);
        ci0[j] = gj * PATCH + ca;
        ci1[j] = gj * PATCH + min(ca + 1, 223);
        ci2[j] = gj * PATCH + min(ca + 2, 223);
    }

    // block-uniform patch-row range (a0 monotone in y)
    const int pr_min = __float_as_int(make_entry(y0, ch, tp).w);
    const int pr_max = min(__float_as_int(make_entry(y0 + ROWS - 1, ch, tp).w) + 2, 223);
    const int nrows  = pr_max - pr_min + 1;   // <= MAXPR

    // row entries for this thread's 4 rows
    float rwx[4], rwy[4], rwz[4];
    int rk0[4], rk1[4], rk2[4];
    #pragma unroll
    for (int j = 0; j < 4; ++j) {
        float4 e = make_entry(y0 + sub + 4 * j, ch, tp);
        rwx[j] = e.x; rwy[j] = e.y; rwz[j] = e.z;
        int ra = __float_as_int(e.w);
        rk0[j] = ra - pr_min;
        rk1[j] = min(ra + 1, 223) - pr_min;
        rk2[j] = min(ra + 2, 223) - pr_min;
    }

    const float* xb = x + (size_t)b * 3 * IMG * IMG + (size_t)(gi * PATCH + pr_min) * IMG;
    float* ob = out + (size_t)n * 3 * IMG * IMG;

    for (int c = 0; c < 3; ++c) {
        const float* xc = xb + (size_t)c * IMG * IMG;
        // horizontal pass: each needed patch row interpolated once (float4/lane)
        #pragma unroll
        for (int i = 0; i < 3; ++i) {
            int k = sub + 4 * i;
            if (k < nrows) {
                const float* xr = xc + (size_t)k * IMG;
                float4 h;
                h.x = cwx[0] * xr[ci0[0]] + cwy[0] * xr[ci1[0]] + cwz[0] * xr[ci2[0]];
                h.y = cwx[1] * xr[ci0[1]] + cwy[1] * xr[ci1[1]] + cwz[1] * xr[ci2[1]];
                h.z = cwx[2] * xr[ci0[2]] + cwy[2] * xr[ci1[2]] + cwz[2] * xr[ci2[2]];
                h.w = cwx[3] * xr[ci0[3]] + cwy[3] * xr[ci1[3]] + cwz[3] * xr[ci2[3]];
                *reinterpret_cast<float4*>(&hrow[k][4 * q]) = h;
            }
        }
        __syncthreads();
        // vertical pass: 3x ds_read_b128 + 1x global_store_dwordx4 per 4 pixels
        #pragma unroll
        for (int j = 0; j < 4; ++j) {
            const float4 A = *reinterpret_cast<const float4*>(&hrow[rk0[j]][4 * q]);
            const float4 Bv = *reinterpret_cast<const float4*>(&hrow[rk1[j]][4 * q]);
            const float4 Cv = *reinterpret_cast<const float4*>(&hrow[rk2[j]][4 * q]);
            float4 v;
            v.x = rwx[j] * A.x + rwy[j] * Bv.x + rwz[j] * Cv.x;
            v.y = rwx[j] * A.y + rwy[j] * Bv.y + rwz[j] * Cv.y;
            v.z = rwx[j] * A.z + rwy[j] * Bv.z + rwz[j] * Cv.z;
            v.w = rwx[j] * A.w + rwy[j] * Bv.w + rwz[j] * Cv.w;
            *reinterpret_cast<float4*>(
                &ob[((size_t)c * IMG + (y0 + sub + 4 * j)) * IMG + 4 * q]) = v;
        }
        __syncthreads();
    }
}

extern "C" void kernel_launch(void* const* d_in, const int* in_sizes, int n_in,
                              void* d_out, int out_size, void* d_ws, size_t ws_size,
                              hipStream_t stream) {
    const float* x        = (const float*)d_in[0];
    const int*   tops     = (const int*)d_in[1];
    const int*   lefts    = (const int*)d_in[2];
    const int*   crop_hs  = (const int*)d_in[3];
    const int*   crop_ws  = (const int*)d_in[4];
    float*       out      = (float*)d_out;

    dim3 grid(IMG / ROWS, 128);   // 28 x 128 blocks
    dim3 block(IMG);              // 448 threads = 7 waves
    roi_patch_kernel<<<grid, block, 0, stream>>>(x, tops, lefts, crop_hs, crop_ws,
                                                 out, out_size);
}

// Round 4
// 146.064 us; speedup vs baseline: 1.0235x; 1.0235x over previous
//
#include <hip/hip_runtime.h>

// ROIPatchExtractor: B=32, C=3, H=W=448, 2x2 patches -> N=128 samples.
// Composed separable bilinear (patch->448 upsample, then ROI crop+resize):
// each output row/col = weighted 3-tap sum of consecutive patch rows/cols.
// Two-pass per block: horizontal pass interpolates each needed patch row once
// into LDS (float4 lanes), vertical pass = 3x ds_read_b128 + dwordx4 store.
// Entry tables are computed COOPERATIVELY (1 make_entry per thread) into an
// LDS SoA-of-quads layout so readback is conflict-free ds_read_b128 --
// round 3's regression was 10x make_entry per thread in the prologue.
// Thread layout: 448 threads = 112 column-quads (q=tid%112, cols 4q..4q+3)
//                x 4 row-subsets (sub=tid/112, rows sub+4j of the 16-row tile).

#define IMG 448
#define PATCH 224
#define ROWS 16
#define MAXPR 12   // patch rows per 16-output-row tile: <= 8+3
#define RPAD 452   // hrow stride in floats (16B-aligned)
#define NQ 112

__device__ inline float4 make_entry(int t, int crop, int off) {
    // stage 2: output coord t -> up-image coords u0,u1 with weight wy
    float cf = (float)crop;
    float s = ((float)t + 0.5f) * cf / 448.0f - 0.5f;
    s = fminf(fmaxf(s, 0.0f), cf - 1.0f);
    int i0 = (int)s;                 // s >= 0, trunc == floor
    int i1 = min(i0 + 1, crop - 1);
    float wy = s - (float)i0;
    int u0 = off + i0;
    int u1 = off + i1;
    // stage 1: up coord u -> patch coord: s1 = 0.5*u - 0.25, clamp [0,223]
    float t0 = fminf(fmaxf(0.5f * (float)u0 - 0.25f, 0.0f), 223.0f);
    int a0 = (int)t0;
    int a1 = min(a0 + 1, 223);
    float f0 = t0 - (float)a0;
    float t1 = fminf(fmaxf(0.5f * (float)u1 - 0.25f, 0.0f), 223.0f);
    int b0 = (int)t1;
    int b1 = min(b0 + 1, 223);
    float f1 = t1 - (float)b0;
    // fold 4 taps into 3 slots relative to a0 (footprint <= a0+2)
    float g0 = (1.0f - wy) * (1.0f - f0);
    float g1 = (1.0f - wy) * f0;
    float g2 = wy * (1.0f - f1);
    float g3 = wy * f1;
    float w0 = g0, w1 = 0.0f, w2 = 0.0f;
    if (a1 == a0) w0 += g1; else w1 += g1;
    if (b0 == a0) w0 += g2; else w1 += g2;
    int ob1 = b1 - a0;
    if (ob1 == 0) w0 += g3; else if (ob1 == 1) w1 += g3; else w2 += g3;
    float4 e;
    e.x = w0; e.y = w1; e.z = w2;
    e.w = __int_as_float(a0);        // patch-local base index [0,223]
    return e;
}

__global__ __launch_bounds__(448)
void roi_patch_kernel(const float* __restrict__ x,
                      const int* __restrict__ tops,
                      const int* __restrict__ lefts,
                      const int* __restrict__ crop_hs,
                      const int* __restrict__ crop_ws,
                      float* __restrict__ out,
                      int out_size) {
    __shared__ __align__(16) float  hrow[MAXPR][RPAD];
    __shared__ float4 wx4[NQ], wy4[NQ], wz4[NQ];
    __shared__ int4   ib4[NQ];
    __shared__ float4 rowE[ROWS];

    const int n   = blockIdx.y;
    const int y0  = blockIdx.x * ROWS;
    const int tid = threadIdx.x;
    const int b   = n >> 2;
    const int gi  = (n >> 1) & 1;
    const int gj  = n & 1;

    const int ch = crop_hs[n], cw = crop_ws[n];
    const int tp = tops[n],    lf = lefts[n];

    const int q   = tid % NQ;    // column quad: cols 4q..4q+3
    const int sub = tid / NQ;    // row subset: rows sub + 4j

    // patch_indices tail (float values; harness reads flat buffer as f32)
    if (blockIdx.x == 0 && n == 0 && tid < 128) {
        out[(size_t)out_size - 128 + tid] = (float)(tid & 3);
    }

    // ---- phase A: cooperative entry tables (1 make_entry per thread) ----
    {
        float4 e = make_entry(tid, cw, lf);
        ((float*)wx4)[tid] = e.x;
        ((float*)wy4)[tid] = e.y;
        ((float*)wz4)[tid] = e.z;
        ((int*)ib4)[tid]   = __float_as_int(e.w);
        if (tid < ROWS) rowE[tid] = make_entry(y0 + tid, ch, tp);
    }
    __syncthreads();

    // ---- phase B: conflict-free readback (stride-16B b128 reads) ----
    const float4 cwx = wx4[q], cwy = wy4[q], cwz = wz4[q];
    const int4   ib  = ib4[q];
    const int cb = gj * PATCH;
    const int ci0[4] = { cb + ib.x, cb + ib.y, cb + ib.z, cb + ib.w };
    const int ci1[4] = { cb + min(ib.x + 1, 223), cb + min(ib.y + 1, 223),
                         cb + min(ib.z + 1, 223), cb + min(ib.w + 1, 223) };
    const int ci2[4] = { cb + min(ib.x + 2, 223), cb + min(ib.y + 2, 223),
                         cb + min(ib.z + 2, 223), cb + min(ib.w + 2, 223) };
    const float cwa[4] = { cwx.x, cwx.y, cwx.z, cwx.w };
    const float cwb[4] = { cwy.x, cwy.y, cwy.z, cwy.w };
    const float cwc[4] = { cwz.x, cwz.y, cwz.z, cwz.w };

    const int pr_min = __float_as_int(rowE[0].w);
    const int pr_max = min(__float_as_int(rowE[ROWS - 1].w) + 2, 223);
    const int nrows  = pr_max - pr_min + 1;   // <= MAXPR

    // this thread's 4 row entries (broadcast-ish LDS reads, hoisted to regs)
    float rwx[4], rwy[4], rwz[4];
    int rk0[4], rk1[4], rk2[4];
    #pragma unroll
    for (int j = 0; j < 4; ++j) {
        float4 e = rowE[sub + 4 * j];
        rwx[j] = e.x; rwy[j] = e.y; rwz[j] = e.z;
        int ra = __float_as_int(e.w);
        rk0[j] = ra - pr_min;
        rk1[j] = min(ra + 1, 223) - pr_min;
        rk2[j] = min(ra + 2, 223) - pr_min;
    }

    const float* xb = x + (size_t)b * 3 * IMG * IMG + (size_t)(gi * PATCH + pr_min) * IMG;
    float* ob = out + (size_t)n * 3 * IMG * IMG;

    for (int c = 0; c < 3; ++c) {
        const float* xc = xb + (size_t)c * IMG * IMG;
        // horizontal pass: each needed patch row interpolated once (float4/lane)
        #pragma unroll
        for (int i = 0; i < 3; ++i) {
            int k = sub + 4 * i;
            if (i == 0 || k < nrows) {
                const float* xr = xc + (size_t)k * IMG;
                float4 h;
                h.x = cwa[0] * xr[ci0[0]] + cwb[0] * xr[ci1[0]] + cwc[0] * xr[ci2[0]];
                h.y = cwa[1] * xr[ci0[1]] + cwb[1] * xr[ci1[1]] + cwc[1] * xr[ci2[1]];
                h.z = cwa[2] * xr[ci0[2]] + cwb[2] * xr[ci1[2]] + cwc[2] * xr[ci2[2]];
                h.w = cwa[3] * xr[ci0[3]] + cwb[3] * xr[ci1[3]] + cwc[3] * xr[ci2[3]];
                *reinterpret_cast<float4*>(&hrow[k][4 * q]) = h;
            }
        }
        __syncthreads();
        // vertical pass: 3x ds_read_b128 + 1x global_store_dwordx4 per 4 pixels
        #pragma unroll
        for (int j = 0; j < 4; ++j) {
            const float4 A  = *reinterpret_cast<const float4*>(&hrow[rk0[j]][4 * q]);
            const float4 Bv = *reinterpret_cast<const float4*>(&hrow[rk1[j]][4 * q]);
            const float4 Cv = *reinterpret_cast<const float4*>(&hrow[rk2[j]][4 * q]);
            float4 v;
            v.x = rwx[j] * A.x + rwy[j] * Bv.x + rwz[j] * Cv.x;
            v.y = rwx[j] * A.y + rwy[j] * Bv.y + rwz[j] * Cv.y;
            v.z = rwx[j] * A.z + rwy[j] * Bv.z + rwz[j] * Cv.z;
            v.w = rwx[j] * A.w + rwy[j] * Bv.w + rwz[j] * Cv.w;
            *reinterpret_cast<float4*>(
                &ob[((size_t)c * IMG + (y0 + sub + 4 * j)) * IMG + 4 * q]) = v;
        }
        if (c != 2) __syncthreads();
    }
}

extern "C" void kernel_launch(void* const* d_in, const int* in_sizes, int n_in,
                              void* d_out, int out_size, void* d_ws, size_t ws_size,
                              hipStream_t stream) {
    const float* x        = (const float*)d_in[0];
    const int*   tops     = (const int*)d_in[1];
    const int*   lefts    = (const int*)d_in[2];
    const int*   crop_hs  = (const int*)d_in[3];
    const int*   crop_ws  = (const int*)d_in[4];
    float*       out      = (float*)d_out;

    dim3 grid(IMG / ROWS, 128);   // 28 x 128 blocks
    dim3 block(IMG);              // 448 threads = 7 waves
    roi_patch_kernel<<<grid, block, 0, stream>>>(x, tops, lefts, crop_hs, crop_ws,
                                                 out, out_size);
}

// Round 5
// 141.210 us; speedup vs baseline: 1.0587x; 1.0344x over previous
//
#include <hip/hip_runtime.h>

// ROIPatchExtractor: B=32, C=3, H=W=448, 2x2 patches -> N=128 samples.
// Composed separable bilinear (patch->448 upsample, then ROI crop+resize):
// each output row/col = weighted 3-tap sum of consecutive patch rows/cols.
//
// HYBRID layout (post-mortem r3/r4: quad-column gathers quadrupled per-wave
// L1 segment count; col-per-thread gathers are lane-adjacent):
//  - horizontal pass: col-per-thread (col = tid), 3 lane-adjacent gathers +
//    ds_write_b32 (2 lanes/bank = free) per patch row.
//  - vertical pass:   quad layout (q=tid%112, sub=tid/112): 3x ds_read_b128 +
//    1x global_store_dwordx4 per 4 pixels.

#define IMG 448
#define PATCH 224
#define ROWS 16
#define MAXPR 12   // patch rows per 16-output-row tile: <= 8+3
#define RPAD 452   // hrow stride in floats (16B-aligned: 452*4=1808, /16 ok)
#define NQ 112

__device__ inline float4 make_entry(int t, int crop, int off) {
    // stage 2: output coord t -> up-image coords u0,u1 with weight wy
    float cf = (float)crop;
    float s = ((float)t + 0.5f) * cf / 448.0f - 0.5f;
    s = fminf(fmaxf(s, 0.0f), cf - 1.0f);
    int i0 = (int)s;                 // s >= 0, trunc == floor
    int i1 = min(i0 + 1, crop - 1);
    float wy = s - (float)i0;
    int u0 = off + i0;
    int u1 = off + i1;
    // stage 1: up coord u -> patch coord: s1 = 0.5*u - 0.25, clamp [0,223]
    float t0 = fminf(fmaxf(0.5f * (float)u0 - 0.25f, 0.0f), 223.0f);
    int a0 = (int)t0;
    int a1 = min(a0 + 1, 223);
    float f0 = t0 - (float)a0;
    float t1 = fminf(fmaxf(0.5f * (float)u1 - 0.25f, 0.0f), 223.0f);
    int b0 = (int)t1;
    int b1 = min(b0 + 1, 223);
    float f1 = t1 - (float)b0;
    // fold 4 taps into 3 slots relative to a0 (footprint <= a0+2)
    float g0 = (1.0f - wy) * (1.0f - f0);
    float g1 = (1.0f - wy) * f0;
    float g2 = wy * (1.0f - f1);
    float g3 = wy * f1;
    float w0 = g0, w1 = 0.0f, w2 = 0.0f;
    if (a1 == a0) w0 += g1; else w1 += g1;
    if (b0 == a0) w0 += g2; else w1 += g2;
    int ob1 = b1 - a0;
    if (ob1 == 0) w0 += g3; else if (ob1 == 1) w1 += g3; else w2 += g3;
    float4 e;
    e.x = w0; e.y = w1; e.z = w2;
    e.w = __int_as_float(a0);        // patch-local base index [0,223]
    return e;
}

__global__ __launch_bounds__(448)
void roi_patch_kernel(const float* __restrict__ x,
                      const int* __restrict__ tops,
                      const int* __restrict__ lefts,
                      const int* __restrict__ crop_hs,
                      const int* __restrict__ crop_ws,
                      float* __restrict__ out,
                      int out_size) {
    __shared__ __align__(16) float hrow[MAXPR][RPAD];
    __shared__ float4 rowE[ROWS];

    const int n   = blockIdx.y;
    const int y0  = blockIdx.x * ROWS;
    const int tid = threadIdx.x;
    const int b   = n >> 2;
    const int gi  = (n >> 1) & 1;
    const int gj  = n & 1;

    const int ch = crop_hs[n], cw = crop_ws[n];
    const int tp = tops[n],    lf = lefts[n];

    // per-thread column entry (col = tid) for the horizontal pass -- registers
    const float4 ce = make_entry(tid, cw, lf);
    const int ca = __float_as_int(ce.w);
    const int cb = gj * PATCH;
    const int c0 = cb + ca;
    const int c1 = cb + min(ca + 1, 223);
    const int c2 = cb + min(ca + 2, 223);

    if (tid < ROWS) rowE[tid] = make_entry(y0 + tid, ch, tp);

    // patch_indices tail (float values; harness reads flat buffer as f32)
    if (blockIdx.x == 0 && n == 0 && tid < 128) {
        out[(size_t)out_size - 128 + tid] = (float)(tid & 3);
    }
    __syncthreads();

    // block-uniform patch-row range (a0 monotone in y)
    const int pr_min = __float_as_int(rowE[0].w);
    const int pr_max = min(__float_as_int(rowE[ROWS - 1].w) + 2, 223);
    const int nrows  = pr_max - pr_min + 1;   // <= MAXPR

    // vertical-pass thread mapping: quad of 4 cols x 4 of the 16 rows
    const int q   = tid % NQ;    // cols 4q..4q+3
    const int sub = tid / NQ;    // rows sub + 4j
    float rwx[4], rwy[4], rwz[4];
    int rk0[4], rk1[4], rk2[4];
    #pragma unroll
    for (int j = 0; j < 4; ++j) {
        float4 e = rowE[sub + 4 * j];   // wave-uniform-ish broadcast read
        rwx[j] = e.x; rwy[j] = e.y; rwz[j] = e.z;
        int ra = __float_as_int(e.w);
        rk0[j] = ra - pr_min;
        rk1[j] = min(ra + 1, 223) - pr_min;
        rk2[j] = min(ra + 2, 223) - pr_min;
    }

    const float* xb = x + (size_t)b * 3 * IMG * IMG + (size_t)(gi * PATCH + pr_min) * IMG;
    float* ob = out + (size_t)n * 3 * IMG * IMG;

    for (int c = 0; c < 3; ++c) {
        const float* xc = xb + (size_t)c * IMG * IMG;
        // horizontal pass: col-per-thread, lane-adjacent gathers
        for (int k = 0; k < nrows; ++k) {
            const float* xr = xc + (size_t)k * IMG;
            hrow[k][tid] = ce.x * xr[c0] + ce.y * xr[c1] + ce.z * xr[c2];
        }
        __syncthreads();
        // vertical pass: 3x ds_read_b128 + 1x global_store_dwordx4 per 4 pixels
        #pragma unroll
        for (int j = 0; j < 4; ++j) {
            const float4 A  = *reinterpret_cast<const float4*>(&hrow[rk0[j]][4 * q]);
            const float4 Bv = *reinterpret_cast<const float4*>(&hrow[rk1[j]][4 * q]);
            const float4 Cv = *reinterpret_cast<const float4*>(&hrow[rk2[j]][4 * q]);
            float4 v;
            v.x = rwx[j] * A.x + rwy[j] * Bv.x + rwz[j] * Cv.x;
            v.y = rwx[j] * A.y + rwy[j] * Bv.y + rwz[j] * Cv.y;
            v.z = rwx[j] * A.z + rwy[j] * Bv.z + rwz[j] * Cv.z;
            v.w = rwx[j] * A.w + rwy[j] * Bv.w + rwz[j] * Cv.w;
            *reinterpret_cast<float4*>(
                &ob[((size_t)c * IMG + (y0 + sub + 4 * j)) * IMG + 4 * q]) = v;
        }
        if (c != 2) __syncthreads();
    }
}

extern "C" void kernel_launch(void* const* d_in, const int* in_sizes, int n_in,
                              void* d_out, int out_size, void* d_ws, size_t ws_size,
                              hipStream_t stream) {
    const float* x        = (const float*)d_in[0];
    const int*   tops     = (const int*)d_in[1];
    const int*   lefts    = (const int*)d_in[2];
    const int*   crop_hs  = (const int*)d_in[3];
    const int*   crop_ws  = (const int*)d_in[4];
    float*       out      = (float*)d_out;

    dim3 grid(IMG / ROWS, 128);   // 28 x 128 blocks
    dim3 block(IMG);              // 448 threads = 7 waves
    roi_patch_kernel<<<grid, block, 0, stream>>>(x, tops, lefts, crop_hs, crop_ws,
                                                 out, out_size);
}

// Round 6
// 126.962 us; speedup vs baseline: 1.1775x; 1.1122x over previous
//
#include <hip/hip_runtime.h>

// ROIPatchExtractor: B=32, C=3, H=W=448, 2x2 patches -> N=128 samples.
// Composed separable bilinear (patch->448 upsample, then ROI crop+resize):
// each output row/col = weighted 3-tap sum of consecutive patch rows/cols.
//
// ROLLING-WINDOW kernel (post-mortem r2-r5: hrow LDS was per-thread scratch --
// thread tid wrote hrow[k][tid] and only thread tid read it back. Keep the
// 3-row horizontal-interp window in REGISTERS instead; the window start a0 is
// non-decreasing with <=1 advance per output row, block-uniform).
// Per thread (col = tid), per channel: walk 28 output rows; per row
// 3 FMA + 1 store; on window advance 3 lane-adjacent gathers + 3 FMA.
// No hrow LDS, no per-channel barriers. Only LDS: 28-entry row table.

#define IMG 448
#define PATCH 224
#define ROWS 28    // output rows per block; grid.x = 448/28 = 16

__device__ inline float4 make_entry(int t, int crop, int off) {
    // stage 2: output coord t -> up-image coords u0,u1 with weight wy
    float cf = (float)crop;
    float s = ((float)t + 0.5f) * cf / 448.0f - 0.5f;
    s = fminf(fmaxf(s, 0.0f), cf - 1.0f);
    int i0 = (int)s;                 // s >= 0, trunc == floor
    int i1 = min(i0 + 1, crop - 1);
    float wy = s - (float)i0;
    int u0 = off + i0;
    int u1 = off + i1;
    // stage 1: up coord u -> patch coord: s1 = 0.5*u - 0.25, clamp [0,223]
    float t0 = fminf(fmaxf(0.5f * (float)u0 - 0.25f, 0.0f), 223.0f);
    int a0 = (int)t0;
    int a1 = min(a0 + 1, 223);
    float f0 = t0 - (float)a0;
    float t1 = fminf(fmaxf(0.5f * (float)u1 - 0.25f, 0.0f), 223.0f);
    int b0 = (int)t1;
    int b1 = min(b0 + 1, 223);
    float f1 = t1 - (float)b0;
    // fold 4 taps into 3 slots relative to a0 (footprint <= a0+2)
    float g0 = (1.0f - wy) * (1.0f - f0);
    float g1 = (1.0f - wy) * f0;
    float g2 = wy * (1.0f - f1);
    float g3 = wy * f1;
    float w0 = g0, w1 = 0.0f, w2 = 0.0f;
    if (a1 == a0) w0 += g1; else w1 += g1;
    if (b0 == a0) w0 += g2; else w1 += g2;
    int ob1 = b1 - a0;
    if (ob1 == 0) w0 += g3; else if (ob1 == 1) w1 += g3; else w2 += g3;
    float4 e;
    e.x = w0; e.y = w1; e.z = w2;
    e.w = __int_as_float(a0);        // patch-local base index [0,223]
    return e;
}

__global__ __launch_bounds__(448)
void roi_patch_kernel(const float* __restrict__ x,
                      const int* __restrict__ tops,
                      const int* __restrict__ lefts,
                      const int* __restrict__ crop_hs,
                      const int* __restrict__ crop_ws,
                      float* __restrict__ out,
                      int out_size) {
    __shared__ float4 rowE[ROWS];

    const int n   = blockIdx.y;
    const int y0  = blockIdx.x * ROWS;
    const int tid = threadIdx.x;
    const int b   = n >> 2;
    const int gi  = (n >> 1) & 1;
    const int gj  = n & 1;

    const int ch = crop_hs[n], cw = crop_ws[n];
    const int tp = tops[n],    lf = lefts[n];

    // per-thread column entry (col = tid) -- registers
    const float4 ce = make_entry(tid, cw, lf);
    const int ca = __float_as_int(ce.w);
    const int cb = gj * PATCH;
    const int c0 = cb + ca;
    const int c1 = cb + min(ca + 1, 223);
    const int c2 = cb + min(ca + 2, 223);

    if (tid < ROWS) rowE[tid] = make_entry(y0 + tid, ch, tp);

    // patch_indices tail (float values; harness reads flat buffer as f32)
    if (blockIdx.x == 0 && n == 0 && tid < 128) {
        out[(size_t)out_size - 128 + tid] = (float)(tid & 3);
    }
    __syncthreads();

    // base of this sample's patch rows (gi selects top/bottom half)
    const float* xb = x + (size_t)b * 3 * IMG * IMG + (size_t)(gi * PATCH) * IMG;
    float* ob = out + (size_t)n * 3 * IMG * IMG;

    const int p_start = __float_as_int(rowE[0].w);   // a0 of first row (uniform)

    for (int c = 0; c < 3; ++c) {
        const float* xc = xb + (size_t)c * IMG * IMG;

        // init 3-row register window at patch row p_start
        int p = p_start;
        const float* xr0 = xc + (size_t)p * IMG;
        const float* xr1 = xc + (size_t)min(p + 1, 223) * IMG;
        const float* xr2 = xc + (size_t)min(p + 2, 223) * IMG;
        float h0 = ce.x * xr0[c0] + ce.y * xr0[c1] + ce.z * xr0[c2];
        float h1 = ce.x * xr1[c0] + ce.y * xr1[c1] + ce.z * xr1[c2];
        float h2 = ce.x * xr2[c0] + ce.y * xr2[c1] + ce.z * xr2[c2];

        float* orow = ob + ((size_t)c * IMG + y0) * IMG + tid;

        #pragma unroll 4
        for (int r = 0; r < ROWS; ++r) {
            const float4 re = rowE[r];
            const int ra = __float_as_int(re.w);
            while (p < ra) {               // block-uniform, <=1 iter per row
                ++p;
                h0 = h1; h1 = h2;
                const float* xr = xc + (size_t)min(p + 2, 223) * IMG;
                h2 = ce.x * xr[c0] + ce.y * xr[c1] + ce.z * xr[c2];
            }
            *orow = re.x * h0 + re.y * h1 + re.z * h2;
            orow += IMG;
        }
    }
}

extern "C" void kernel_launch(void* const* d_in, const int* in_sizes, int n_in,
                              void* d_out, int out_size, void* d_ws, size_t ws_size,
                              hipStream_t stream) {
    const float* x        = (const float*)d_in[0];
    const int*   tops     = (const int*)d_in[1];
    const int*   lefts    = (const int*)d_in[2];
    const int*   crop_hs  = (const int*)d_in[3];
    const int*   crop_ws  = (const int*)d_in[4];
    float*       out      = (float*)d_out;

    dim3 grid(IMG / ROWS, 128);   // 16 x 128 blocks
    dim3 block(IMG);              // 448 threads = 7 waves
    roi_patch_kernel<<<grid, block, 0, stream>>>(x, tops, lefts, crop_hs, crop_ws,
                                                 out, out_size);
}

// Round 7
// 108.596 us; speedup vs baseline: 1.3767x; 1.1691x over previous
//
#include <hip/hip_runtime.h>

// ROIPatchExtractor: B=32, C=3, H=W=448, 2x2 patches -> N=128 samples.
// Composed separable bilinear (patch->448 upsample, then ROI crop+resize):
// each output row/col = weighted 3-tap sum of <=3 consecutive patch rows/cols.
//
// Channel-pipelined double-buffer design (post-mortems r2-r6):
//  - r2 (113us): independent gathers (MLP) but 6 barriers serialize
//    store-phase vs gather-phase.   - r3/r4: quad-gathers -> 4x L1 span, lost.
//  - r6: rolling register window -> serial load chain, no MLP, lost.
//  Here: col-per-thread gathers (lane-adjacent), ROWS=8 so MAXPR=8 and two
//  LDS buffers fit 4 blocks/CU; per phase: issue NEXT channel's gathers into
//  regs (independent), run CURRENT channel's vpass (LDS+FMA+stores), then
//  ds_write the gathered rows. 4 barriers/block, phases overlap pipes.

#define IMG 448
#define PATCH 224
#define ROWS 8     // output rows per block; grid.x = 448/8 = 56
#define MAXPR 8    // patch-row footprint for 8 output rows: a0 span<=4, +3 taps

__device__ inline float4 make_entry(int t, int crop, int off) {
    // stage 2: output coord t -> up-image coords u0,u1 with weight wy
    float cf = (float)crop;
    float s = ((float)t + 0.5f) * cf / 448.0f - 0.5f;
    s = fminf(fmaxf(s, 0.0f), cf - 1.0f);
    int i0 = (int)s;                 // s >= 0, trunc == floor
    int i1 = min(i0 + 1, crop - 1);
    float wy = s - (float)i0;
    int u0 = off + i0;
    int u1 = off + i1;
    // stage 1: up coord u -> patch coord: s1 = 0.5*u - 0.25, clamp [0,223]
    float t0 = fminf(fmaxf(0.5f * (float)u0 - 0.25f, 0.0f), 223.0f);
    int a0 = (int)t0;
    int a1 = min(a0 + 1, 223);
    float f0 = t0 - (float)a0;
    float t1 = fminf(fmaxf(0.5f * (float)u1 - 0.25f, 0.0f), 223.0f);
    int b0 = (int)t1;
    int b1 = min(b0 + 1, 223);
    float f1 = t1 - (float)b0;
    // fold 4 taps into 3 slots relative to a0 (footprint <= a0+2)
    float g0 = (1.0f - wy) * (1.0f - f0);
    float g1 = (1.0f - wy) * f0;
    float g2 = wy * (1.0f - f1);
    float g3 = wy * f1;
    float w0 = g0, w1 = 0.0f, w2 = 0.0f;
    if (a1 == a0) w0 += g1; else w1 += g1;
    if (b0 == a0) w0 += g2; else w1 += g2;
    int ob1 = b1 - a0;
    if (ob1 == 0) w0 += g3; else if (ob1 == 1) w1 += g3; else w2 += g3;
    float4 e;
    e.x = w0; e.y = w1; e.z = w2;
    e.w = __int_as_float(a0);        // patch-local base index [0,223]
    return e;
}

__global__ __launch_bounds__(448)
void roi_patch_kernel(const float* __restrict__ x,
                      const int* __restrict__ tops,
                      const int* __restrict__ lefts,
                      const int* __restrict__ crop_hs,
                      const int* __restrict__ crop_ws,
                      float* __restrict__ out,
                      int out_size) {
    __shared__ float  hA[MAXPR][IMG];
    __shared__ float  hB[MAXPR][IMG];
    __shared__ float4 rowE[ROWS];

    const int n   = blockIdx.y;
    const int y0  = blockIdx.x * ROWS;
    const int tid = threadIdx.x;
    const int b   = n >> 2;
    const int gi  = (n >> 1) & 1;
    const int gj  = n & 1;

    const int ch = crop_hs[n], cw = crop_ws[n];
    const int tp = tops[n],    lf = lefts[n];

    // per-thread column entry (col = tid) -- registers
    const float4 ce = make_entry(tid, cw, lf);
    const int ca = __float_as_int(ce.w);
    const int cb = gj * PATCH;
    const int c0 = cb + ca;
    const int c1 = cb + min(ca + 1, 223);
    const int c2 = cb + min(ca + 2, 223);

    if (tid < ROWS) rowE[tid] = make_entry(y0 + tid, ch, tp);

    // patch_indices tail (float values; harness reads flat buffer as f32)
    if (blockIdx.x == 0 && n == 0 && tid < 128) {
        out[(size_t)out_size - 128 + tid] = (float)(tid & 3);
    }
    __syncthreads();

    const int pr_min = __float_as_int(rowE[0].w);
    const int pr_max = min(__float_as_int(rowE[ROWS - 1].w) + 2, 223);
    const int nrows  = pr_max - pr_min + 1;   // <= MAXPR

    const float* xb = x + (size_t)b * 3 * IMG * IMG + (size_t)(gi * PATCH + pr_min) * IMG;
    float* ob = out + (size_t)n * 3 * IMG * IMG + (size_t)y0 * IMG + tid;

    float v0[MAXPR], v1[MAXPR], v2[MAXPR];

    // ---- macro helpers (unrolled, static reg indexing) ----
#define GATHER(CH)                                                        \
    {                                                                     \
        const float* xc = xb + (size_t)(CH) * IMG * IMG;                  \
        _Pragma("unroll")                                                 \
        for (int k = 0; k < MAXPR; ++k) {                                 \
            if (k < nrows) {                                              \
                const float* xr = xc + (size_t)k * IMG;                   \
                v0[k] = xr[c0]; v1[k] = xr[c1]; v2[k] = xr[c2];           \
            }                                                             \
        }                                                                 \
    }

#define HWRITE(BUF)                                                       \
    {                                                                     \
        _Pragma("unroll")                                                 \
        for (int k = 0; k < MAXPR; ++k) {                                 \
            if (k < nrows) {                                              \
                BUF[k][tid] = ce.x * v0[k] + ce.y * v1[k] + ce.z * v2[k]; \
            }                                                             \
        }                                                                 \
    }

#define VPASS(BUF, CH)                                                    \
    {                                                                     \
        float* orow = ob + (size_t)(CH) * IMG * IMG;                      \
        _Pragma("unroll")                                                 \
        for (int r = 0; r < ROWS; ++r) {                                  \
            const float4 re = rowE[r];                                    \
            const int ra = __float_as_int(re.w);                          \
            const int k0 = ra - pr_min;                                   \
            const int k1 = min(ra + 1, 223) - pr_min;                     \
            const int k2 = min(ra + 2, 223) - pr_min;                     \
            *orow = re.x * BUF[k0][tid] + re.y * BUF[k1][tid]             \
                  + re.z * BUF[k2][tid];                                  \
            orow += IMG;                                                  \
        }                                                                 \
    }

    // prologue: channel 0 -> hA
    GATHER(0);
    HWRITE(hA);
    __syncthreads();

    // phase 1: gather ch1 || vpass ch0 ; write hB
    GATHER(1);
    VPASS(hA, 0);
    HWRITE(hB);
    __syncthreads();

    // phase 2: gather ch2 || vpass ch1 ; write hA
    GATHER(2);
    VPASS(hB, 1);
    HWRITE(hA);
    __syncthreads();

    // epilogue: vpass ch2
    VPASS(hA, 2);

#undef GATHER
#undef HWRITE
#undef VPASS
}

extern "C" void kernel_launch(void* const* d_in, const int* in_sizes, int n_in,
                              void* d_out, int out_size, void* d_ws, size_t ws_size,
                              hipStream_t stream) {
    const float* x        = (const float*)d_in[0];
    const int*   tops     = (const int*)d_in[1];
    const int*   lefts    = (const int*)d_in[2];
    const int*   crop_hs  = (const int*)d_in[3];
    const int*   crop_ws  = (const int*)d_in[4];
    float*       out      = (float*)d_out;

    dim3 grid(IMG / ROWS, 128);   // 56 x 128 blocks
    dim3 block(IMG);              // 448 threads = 7 waves
    roi_patch_kernel<<<grid, block, 0, stream>>>(x, tops, lefts, crop_hs, crop_ws,
                                                 out, out_size);
}